// Round 7
// baseline (283.044 us; speedup 1.0000x reference)
//
#include <hip/hip_runtime.h>
#include <stdint.h>

typedef __bf16 bf16;
typedef __bf16 bf16x4_t __attribute__((ext_vector_type(4)));
typedef __bf16 bf16x8_t __attribute__((ext_vector_type(8)));
typedef float f32x4 __attribute__((ext_vector_type(4)));

static constexpr int NB = 2, SS = 2048, DD = 1024, NH = 16, HD = 64;

__device__ __forceinline__ void gl_lds16(const void* g, void* l) {
    __builtin_amdgcn_global_load_lds((__attribute__((address_space(1))) void*)g,
                                     (__attribute__((address_space(3))) void*)l, 16, 0, 0);
}

// ---------------- fused fp32 -> bf16 cast of h + Wq + Wk + Wv + Wo ----------------
__global__ __launch_bounds__(256) void cast_all(const float* __restrict__ h,
                                                const float* __restrict__ Wq,
                                                const float* __restrict__ Wk,
                                                const float* __restrict__ Wv,
                                                const float* __restrict__ Wo,
                                                bf16* __restrict__ dst) {
    int i = blockIdx.x * 256 + threadIdx.x;  // float4 index, grid covers exactly 2097152
    const float* src;
    int off;
    if (i < 1048576) { src = h; off = i; }
    else {
        int r = i - 1048576;
        int w = r >> 18;
        off = r & 262143;
        src = (w == 0) ? Wq : (w == 1) ? Wk : (w == 2) ? Wv : Wo;
    }
    float4 v = reinterpret_cast<const float4*>(src)[off];
    bf16x4_t o;
    o.x = (bf16)v.x; o.y = (bf16)v.y; o.z = (bf16)v.z; o.w = (bf16)v.w;
    reinterpret_cast<bf16x4_t*>(dst)[i] = o;
}

// ---------------- 128x128 NT-GEMM mainloop (m97 structure) ----------------
__device__ __forceinline__ void gemm128_mainloop(const bf16* __restrict__ Ablk,
                                                 const bf16* __restrict__ Bblk,
                                                 int K, f32x4 acc[4][4]) {
    __shared__ __align__(16) bf16 As[128 * 32];
    __shared__ __align__(16) bf16 Bs[128 * 32];
    const int tid = threadIdx.x;
    const int wave = tid >> 6, lane = tid & 63;
    const int quad = lane >> 4, l15 = lane & 15;
    const int wm = wave >> 1, wn = wave & 1;

#pragma unroll
    for (int mi = 0; mi < 4; mi++)
#pragma unroll
        for (int ni = 0; ni < 4; ni++) {
            acc[mi][ni][0] = 0.f; acc[mi][ni][1] = 0.f;
            acc[mi][ni][2] = 0.f; acc[mi][ni][3] = 0.f;
        }

    const int n0c = tid;
    const int r0 = n0c >> 2, c0 = (n0c & 3) ^ ((r0 >> 1) & 3);
    const int n1c = 256 + tid;
    const int r1 = n1c >> 2, c1 = (n1c & 3) ^ ((r1 >> 1) & 3);

    for (int kk = 0; kk < K; kk += 32) {
        __syncthreads();
        gl_lds16(Ablk + (size_t)r0 * K + kk + c0 * 8, &As[(wave * 64) * 8]);
        gl_lds16(Ablk + (size_t)r1 * K + kk + c1 * 8, &As[(256 + wave * 64) * 8]);
        gl_lds16(Bblk + (size_t)r0 * K + kk + c0 * 8, &Bs[(wave * 64) * 8]);
        gl_lds16(Bblk + (size_t)r1 * K + kk + c1 * 8, &Bs[(256 + wave * 64) * 8]);
        __syncthreads();

        bf16x8_t a[4], b[4];
#pragma unroll
        for (int mi = 0; mi < 4; mi++) {
            int R = wm * 64 + mi * 16 + l15;
            a[mi] = *(const bf16x8_t*)&As[R * 32 + ((quad ^ ((R >> 1) & 3)) << 3)];
        }
#pragma unroll
        for (int ni = 0; ni < 4; ni++) {
            int R = wn * 64 + ni * 16 + l15;
            b[ni] = *(const bf16x8_t*)&Bs[R * 32 + ((quad ^ ((R >> 1) & 3)) << 3)];
        }
#pragma unroll
        for (int mi = 0; mi < 4; mi++)
#pragma unroll
            for (int ni = 0; ni < 4; ni++)
                acc[mi][ni] = __builtin_amdgcn_mfma_f32_16x16x32_bf16(a[mi], b[ni], acc[mi][ni], 0, 0, 0);
    }
}

// ---------------- 64x128 NT-GEMM mainloop ----------------
__device__ __forceinline__ void gemm64_mainloop(const bf16* __restrict__ Ablk,
                                                const bf16* __restrict__ Bblk,
                                                int K, f32x4 acc[2][4]) {
    __shared__ __align__(16) bf16 As[64 * 32];
    __shared__ __align__(16) bf16 Bs[128 * 32];
    const int tid = threadIdx.x;
    const int wave = tid >> 6, lane = tid & 63;
    const int quad = lane >> 4, l15 = lane & 15;
    const int wm = wave >> 1, wn = wave & 1;

#pragma unroll
    for (int mi = 0; mi < 2; mi++)
#pragma unroll
        for (int ni = 0; ni < 4; ni++) {
            acc[mi][ni][0] = 0.f; acc[mi][ni][1] = 0.f;
            acc[mi][ni][2] = 0.f; acc[mi][ni][3] = 0.f;
        }

    const int ra = tid >> 2, ca = (tid & 3) ^ ((ra >> 1) & 3);
    const int r0 = tid >> 2, c0 = (tid & 3) ^ ((r0 >> 1) & 3);
    const int n1c = 256 + tid;
    const int r1 = n1c >> 2, c1 = (n1c & 3) ^ ((r1 >> 1) & 3);

    for (int kk = 0; kk < K; kk += 32) {
        __syncthreads();
        gl_lds16(Ablk + (size_t)ra * K + kk + ca * 8, &As[(wave * 64) * 8]);
        gl_lds16(Bblk + (size_t)r0 * K + kk + c0 * 8, &Bs[(wave * 64) * 8]);
        gl_lds16(Bblk + (size_t)r1 * K + kk + c1 * 8, &Bs[(256 + wave * 64) * 8]);
        __syncthreads();

        bf16x8_t a[2], b[4];
#pragma unroll
        for (int mi = 0; mi < 2; mi++) {
            int R = wm * 32 + mi * 16 + l15;
            a[mi] = *(const bf16x8_t*)&As[R * 32 + ((quad ^ ((R >> 1) & 3)) << 3)];
        }
#pragma unroll
        for (int ni = 0; ni < 4; ni++) {
            int R = wn * 64 + ni * 16 + l15;
            b[ni] = *(const bf16x8_t*)&Bs[R * 32 + ((quad ^ ((R >> 1) & 3)) << 3)];
        }
#pragma unroll
        for (int mi = 0; mi < 2; mi++)
#pragma unroll
            for (int ni = 0; ni < 4; ni++)
                acc[mi][ni] = __builtin_amdgcn_mfma_f32_16x16x32_bf16(a[mi], b[ni], acc[mi][ni], 0, 0, 0);
    }
}

// ---------------- QKV projection ----------------
// Q is pre-scaled by 0.125 * log2(e) so attention can use exp2 directly.
__global__ __launch_bounds__(256) void gemm_qkv(const bf16* __restrict__ A, const bf16* __restrict__ Wqkv,
                                                const float* __restrict__ bq, const float* __restrict__ bk,
                                                const float* __restrict__ bv,
                                                bf16* __restrict__ Qb, bf16* __restrict__ Kb, bf16* __restrict__ Vb) {
    const int m0 = blockIdx.x * 128;
    const int n0 = blockIdx.y * 128;
    f32x4 acc[4][4];
    gemm128_mainloop(A + (size_t)m0 * DD, Wqkv + (size_t)n0 * DD, DD, acc);

    const int tid = threadIdx.x, wave = tid >> 6, lane = tid & 63;
    const int quad = lane >> 4, l15 = lane & 15;
    const int wm = wave >> 1, wn = wave & 1;

    const int which = n0 >> 10;
    const float* bias = (which == 0) ? bq : (which == 1) ? bk : bv;
    bf16* dst = (which == 0) ? Qb : (which == 1) ? Kb : Vb;
    const float sc = (which == 0) ? 0.18033688f : 1.0f;  // 0.125 * log2(e)

    const int cbase = (n0 & 1023) + wn * 64;
    const int head = cbase >> 6;
    const int bb = m0 >> 11;
    const int s0 = (m0 & 2047) + wm * 64;
    bf16* dbase = dst + ((size_t)(bb * NH + head)) * SS * HD;

#pragma unroll
    for (int ni = 0; ni < 4; ni++) {
        float bsv = bias[cbase + ni * 16 + l15];
        int hd = ni * 16 + l15;
#pragma unroll
        for (int mi = 0; mi < 4; mi++) {
#pragma unroll
            for (int r = 0; r < 4; r++) {
                int s = s0 + mi * 16 + quad * 4 + r;
                dbase[(size_t)s * HD + hd] = (bf16)((acc[mi][ni][r] + bsv) * sc);
            }
        }
    }
}

// ---------------- output projection: fp32 out, 64x128 tiles ----------------
__global__ __launch_bounds__(256) void gemm_out(const bf16* __restrict__ A, const bf16* __restrict__ Wo,
                                                const float* __restrict__ bo, float* __restrict__ out) {
    const int m0 = blockIdx.x * 64, n0 = blockIdx.y * 128;
    f32x4 acc[2][4];
    gemm64_mainloop(A + (size_t)m0 * DD, Wo + (size_t)n0 * DD, DD, acc);

    const int tid = threadIdx.x, wave = tid >> 6, lane = tid & 63;
    const int quad = lane >> 4, l15 = lane & 15;
    const int wm = wave >> 1, wn = wave & 1;
    float* obase = out + (size_t)(m0 + wm * 32) * DD + n0 + wn * 64;
#pragma unroll
    for (int ni = 0; ni < 4; ni++) {
        float bias = bo[n0 + wn * 64 + ni * 16 + l15];
#pragma unroll
        for (int mi = 0; mi < 2; mi++)
#pragma unroll
            for (int r = 0; r < 4; r++)
                obase[(size_t)(mi * 16 + quad * 4 + r) * DD + ni * 16 + l15] = acc[mi][ni][r] + bias;
    }
}

// ---------------- causal flash attention: static balanced schedule + fused merge ----------------
// bh = bx&31 -> all parts of a head land on XCD bh%8 (K/V working set 2 MB/XCD,
// fits L2 -> low FETCH, the R4 effect). Part table ordered so each CU's triple
// {p, p+8, p+16} sums to exactly 17 j-iters (perfect static balance).
// Split pairs (qtiles 8..15): both halves write unnormalized partials; the
// SECOND to finish (atomicAdd flag handshake, same XCD -> L2-local reads)
// merges and writes Ob. No separate merge kernel.
__global__ __launch_bounds__(256, 3) void attn_kernel(const bf16* __restrict__ Qb, const bf16* __restrict__ Kb,
                                                      const bf16* __restrict__ Vb, bf16* __restrict__ Ob,
                                                      bf16* __restrict__ Opart, float* __restrict__ Ml,
                                                      int* __restrict__ flags) {
    // triples (i, i+8, i+16): 8+8+1, 8+7+2, 8+6+3, 7+6+4, 7+6+4, 7+5+5, 7+5+5, 6+6+5 = 17 each
    constexpr int PQ[24]  = {15,15,14,14,13,13,12,12,  7, 6,11,11,10,10, 9, 5,  0, 1, 2, 3, 8, 9, 8, 4};
    constexpr int PJ0[24] = { 0, 8, 0, 8, 0, 7, 0, 7,  0, 0, 0, 6, 0, 6, 0, 0,  0, 0, 0, 0, 5, 5, 0, 0};
    constexpr int PJ1[24] = { 8,16, 8,15, 7,14, 7,13,  8, 7, 6,12, 6,11, 5, 6,  1, 2, 3, 4, 9,10, 5, 5};

    __shared__ __align__(16) bf16 Kt[128 * 64];    // swizzled, DMA-staged
    __shared__ __align__(16) bf16 Vt[64 * 136];    // V^T [d][key], pad 136
    __shared__ __align__(16) bf16 Pt[4 * 32 * 64]; // per-wave P strips, XOR-swizzled
    __shared__ int s_old;

    const int tid = threadIdx.x, wave = tid >> 6, lane = tid & 63;
    const int quad = lane >> 4, l15 = lane & 15;
    const int bx = blockIdx.x;
    const int p = bx >> 5, bh = bx & 31;
    const int qtile = PQ[p], jbeg = PJ0[p], jend = PJ1[p];
    const bool diagpart = (jend == qtile + 1);
    const size_t hoff = (size_t)bh * SS * HD;
    const bf16* Qg = Qb + hoff + (size_t)qtile * 128 * HD;
    bf16* Pw = &Pt[wave * 2048];

    // Q B-frags (already scaled by 0.125*log2e)
    bf16x8_t qf[2][2];
#pragma unroll
    for (int qt = 0; qt < 2; qt++)
#pragma unroll
        for (int ks = 0; ks < 2; ks++)
            qf[qt][ks] = *(const bf16x8_t*)(Qg + (wave * 32 + qt * 16 + l15) * HD + ks * 32 + quad * 8);

    f32x4 o[2][4];
#pragma unroll
    for (int qt = 0; qt < 2; qt++)
#pragma unroll
        for (int nO = 0; nO < 4; nO++) {
            o[qt][nO][0] = 0.f; o[qt][nO][1] = 0.f; o[qt][nO][2] = 0.f; o[qt][nO][3] = 0.f;
        }
    float mrow[2] = {-__builtin_inff(), -__builtin_inff()};
    float lrow[2] = {0.f, 0.f};

    for (int j = jbeg; j < jend; j++) {
        __syncthreads();
        // K tile DMA, swizzled: row chunk c' holds global chunk c'^(row&7)
        const bf16* Kg = Kb + hoff + (size_t)j * 128 * HD;
#pragma unroll
        for (int t = 0; t < 4; t++) {
            int n = t * 256 + tid;
            int row = n >> 3, gc = (n & 7) ^ (row & 7);
            gl_lds16(Kg + row * HD + gc * 8, &Kt[(t * 256 + wave * 64) * 8]);
        }
        // V transpose staging: 4 x b128 loads -> 8 x b64 writes per thread
        const bf16* Vg = Vb + hoff + (size_t)j * 128 * HD;
        {
            int k0 = (tid & 31) * 4, d0 = (tid >> 5) * 8;
            bf16x8_t v0 = *(const bf16x8_t*)(Vg + (k0 + 0) * HD + d0);
            bf16x8_t v1 = *(const bf16x8_t*)(Vg + (k0 + 1) * HD + d0);
            bf16x8_t v2 = *(const bf16x8_t*)(Vg + (k0 + 2) * HD + d0);
            bf16x8_t v3 = *(const bf16x8_t*)(Vg + (k0 + 3) * HD + d0);
#pragma unroll
            for (int jj = 0; jj < 8; jj++) {
                bf16x4_t w;
                w.x = v0[jj]; w.y = v1[jj]; w.z = v2[jj]; w.w = v3[jj];
                *(bf16x4_t*)&Vt[(d0 + jj) * 136 + k0] = w;
            }
        }
        __syncthreads();

        const bool diag = diagpart && (j == jend - 1);
#pragma unroll 1
        for (int kh = 0; kh < 2; kh++) {
            if (diag && kh == 1 && wave < 2) break;  // rows 0..63 fully masked vs keys 64..127

            // S^T = K * Q^T : st[kt][qt], key = kh*64 + kt*16 + quad*4 + r, qrow = qt*16 + l15
            f32x4 st[4][2];
#pragma unroll
            for (int kt = 0; kt < 4; kt++)
#pragma unroll
                for (int qt = 0; qt < 2; qt++) {
                    st[kt][qt][0] = 0.f; st[kt][qt][1] = 0.f; st[kt][qt][2] = 0.f; st[kt][qt][3] = 0.f;
                }
#pragma unroll
            for (int ks = 0; ks < 2; ks++) {
#pragma unroll
                for (int kt = 0; kt < 4; kt++) {
                    int R = (kh * 4 + kt) * 16 + l15;
                    bf16x8_t kf = *(const bf16x8_t*)&Kt[R * HD + ((((ks << 2) | quad) ^ (R & 7)) << 3)];
#pragma unroll
                    for (int qt = 0; qt < 2; qt++)
                        st[kt][qt] = __builtin_amdgcn_mfma_f32_16x16x32_bf16(kf, qf[qt][ks], st[kt][qt], 0, 0, 0);
                }
            }
            if (diag) {
#pragma unroll
                for (int kt = 0; kt < 4; kt++)
#pragma unroll
                    for (int qt = 0; qt < 2; qt++)
#pragma unroll
                        for (int r = 0; r < 4; r++) {
                            int key = kh * 64 + kt * 16 + quad * 4 + r;
                            int row = wave * 32 + qt * 16 + l15;
                            if (key > row) st[kt][qt][r] = -__builtin_inff();
                        }
            }

            // online softmax (log2 domain)
#pragma unroll
            for (int qt = 0; qt < 2; qt++) {
                float mx = -__builtin_inff();
#pragma unroll
                for (int kt = 0; kt < 4; kt++)
#pragma unroll
                    for (int r = 0; r < 4; r++) mx = fmaxf(mx, st[kt][qt][r]);
                mx = fmaxf(mx, __shfl_xor(mx, 16));
                mx = fmaxf(mx, __shfl_xor(mx, 32));
                float mnew = fmaxf(mrow[qt], mx);
                float alpha = exp2f(mrow[qt] - mnew);
                mrow[qt] = mnew;
                float sum = 0.f;
                const int row = qt * 16 + l15;
#pragma unroll
                for (int kt = 0; kt < 4; kt++) {
                    float p0 = exp2f(st[kt][qt][0] - mnew);
                    float p1 = exp2f(st[kt][qt][1] - mnew);
                    float p2 = exp2f(st[kt][qt][2] - mnew);
                    float p3 = exp2f(st[kt][qt][3] - mnew);
                    sum += (p0 + p1) + (p2 + p3);
                    bf16x4_t pb;
                    pb.x = (bf16)p0; pb.y = (bf16)p1; pb.z = (bf16)p2; pb.w = (bf16)p3;
                    int c = kt * 2 + (quad >> 1);
                    *(bf16x4_t*)&Pw[row * 64 + ((c ^ (row & 7)) << 3) + ((quad & 1) << 2)] = pb;
                }
                sum += __shfl_xor(sum, 16);
                sum += __shfl_xor(sum, 32);
                lrow[qt] = lrow[qt] * alpha + sum;
#pragma unroll
                for (int r = 0; r < 4; r++) {
                    float a = __shfl(alpha, (lane & 48) | (quad * 4 + r));
#pragma unroll
                    for (int nO = 0; nO < 4; nO++) o[qt][nO][r] *= a;
                }
            }

            // O += P * V^T-frags
#pragma unroll
            for (int ks = 0; ks < 2; ks++) {
                bf16x8_t pf[2];
#pragma unroll
                for (int qt = 0; qt < 2; qt++) {
                    int row = qt * 16 + l15;
                    int c = (ks << 2) | quad;
                    pf[qt] = *(const bf16x8_t*)&Pw[row * 64 + ((c ^ (row & 7)) << 3)];
                }
#pragma unroll
                for (int nO = 0; nO < 4; nO++) {
                    bf16x8_t vf = *(const bf16x8_t*)&Vt[(nO * 16 + l15) * 136 + kh * 64 + ks * 32 + quad * 8];
#pragma unroll
                    for (int qt = 0; qt < 2; qt++)
                        o[qt][nO] = __builtin_amdgcn_mfma_f32_16x16x32_bf16(pf[qt], vf, o[qt][nO], 0, 0, 0);
                }
            }
        }
    }

    const int bb = bh >> 4, hh = bh & 15;
    if (qtile >= 8) {
        // split part: write unnormalized O (bf16) + m,l (f32), then handshake
        const int pairidx = (bh << 3) + (qtile - 8);
        const int half = (jbeg != 0) ? 1 : 0;
        const int pidx = pairidx * 2 + half;
        bf16* Op = Opart + (size_t)pidx * (128 * 64);
        float* mlp = Ml + (size_t)pidx * 256;
#pragma unroll
        for (int qt = 0; qt < 2; qt++) {
            if (quad == 0) {
                mlp[wave * 32 + qt * 16 + l15] = mrow[qt];
                mlp[128 + wave * 32 + qt * 16 + l15] = lrow[qt];
            }
#pragma unroll
            for (int r = 0; r < 4; r++) {
                int row = wave * 32 + qt * 16 + quad * 4 + r;
#pragma unroll
                for (int nO = 0; nO < 4; nO++)
                    Op[row * 64 + nO * 16 + l15] = (bf16)o[qt][nO][r];
            }
        }
        __threadfence();   // publish partials before flag bump
        __syncthreads();
        if (tid == 0) s_old = atomicAdd(&flags[pairidx], 1);
        __syncthreads();
        if (s_old == 1) {
            // we are second: merge own registers with partner's partials (L2-local)
            __threadfence();  // acquire partner's writes
            const int pother = pidx ^ 1;
            const bf16* Oo = Opart + (size_t)pother * (128 * 64);
            const float* mlo = Ml + (size_t)pother * 256;
#pragma unroll
            for (int qt = 0; qt < 2; qt++) {
#pragma unroll
                for (int r = 0; r < 4; r++) {
                    int row = wave * 32 + qt * 16 + quad * 4 + r;
                    float m_own = __shfl(mrow[qt], (lane & 48) | (quad * 4 + r));
                    float l_own = __shfl(lrow[qt], (lane & 48) | (quad * 4 + r));
                    float m_p = mlo[row];
                    float l_p = mlo[128 + row];
                    float M = fmaxf(m_own, m_p);
                    float w_own = exp2f(m_own - M), w_p = exp2f(m_p - M);
                    float inv = 1.f / (l_own * w_own + l_p * w_p);
                    int srow = qtile * 128 + row;
#pragma unroll
                    for (int nO = 0; nO < 4; nO++) {
                        float vp = (float)Oo[row * 64 + nO * 16 + l15];
                        float v = (o[qt][nO][r] * w_own + vp * w_p) * inv;
                        Ob[((size_t)(bb * SS + srow)) * DD + hh * HD + nO * 16 + l15] = (bf16)v;
                    }
                }
            }
        }
    } else {
        // whole tile: normalize and write Ob [B, S, H*64]
#pragma unroll
        for (int qt = 0; qt < 2; qt++) {
#pragma unroll
            for (int r = 0; r < 4; r++) {
                float linv = 1.f / __shfl(lrow[qt], (lane & 48) | (quad * 4 + r));
                int srow = qtile * 128 + wave * 32 + qt * 16 + quad * 4 + r;
#pragma unroll
                for (int nO = 0; nO < 4; nO++)
                    Ob[((size_t)(bb * SS + srow)) * DD + hh * HD + nO * 16 + l15] = (bf16)(o[qt][nO][r] * linv);
            }
        }
    }
}

// ---------------- host launcher ----------------
extern "C" void kernel_launch(void* const* d_in, const int* in_sizes, int n_in,
                              void* d_out, int out_size, void* d_ws, size_t ws_size,
                              hipStream_t stream) {
    (void)in_sizes; (void)n_in; (void)out_size; (void)ws_size;
    const float* h  = (const float*)d_in[0];
    const float* Wq = (const float*)d_in[1];
    const float* bq = (const float*)d_in[2];
    const float* Wk = (const float*)d_in[3];
    const float* bk = (const float*)d_in[4];
    const float* Wv = (const float*)d_in[5];
    const float* bv = (const float*)d_in[6];
    const float* Wo = (const float*)d_in[7];
    const float* bo = (const float*)d_in[8];
    float* out = (float*)d_out;

    char* ws = (char*)d_ws;
    bf16* hbf  = (bf16*)(ws);                                  // 8,388,608  h bf16 (dead after gemm_qkv)
    bf16* wqkv = (bf16*)(ws + 8388608);                        // 6,291,456  Wq|Wk|Wv (dead after gemm_qkv)
    bf16* wo   = (bf16*)(ws + 8388608 + 6291456);              // 2,097,152  Wo
    bf16* Qb   = (bf16*)(ws + 16777216);                       // 8,388,608  [B,H,S,64] (scaled)
    bf16* Kb   = (bf16*)(ws + 16777216 + 8388608);
    bf16* Vb   = (bf16*)(ws + 16777216 + 2 * 8388608);
    bf16* Ob   = (bf16*)(ws + 16777216 + 3 * 8388608);         // [B,S,H*64]
    // attention scratch reuses the dead cast region:
    bf16*  Opart = (bf16*)(ws);                                // 512 x 128x64 bf16 = 8,388,608
    float* Ml    = (float*)(ws + 8388608);                     // 512 x 256 f32   =   524,288
    int*   flags = (int*)(ws + 8912896);                       // 256 pair flags (dead wqkv area)

    cast_all<<<8192, 256, 0, stream>>>(h, Wq, Wk, Wv, Wo, hbf);
    gemm_qkv<<<dim3(32, 24), 256, 0, stream>>>(hbf, wqkv, bq, bk, bv, Qb, Kb, Vb);
    hipMemsetAsync(flags, 0, 1024, stream);  // zero pair flags (wqkv dead by now)
    attn_kernel<<<768, 256, 0, stream>>>(Qb, Kb, Vb, Ob, Opart, Ml, flags);
    gemm_out<<<dim3(64, 8), 256, 0, stream>>>(Ob, wo, bo, out);
}

// Round 8
// 187.938 us; speedup vs baseline: 1.5060x; 1.5060x over previous
//
#include <hip/hip_runtime.h>
#include <stdint.h>

typedef __bf16 bf16;
typedef __bf16 bf16x4_t __attribute__((ext_vector_type(4)));
typedef __bf16 bf16x8_t __attribute__((ext_vector_type(8)));
typedef float f32x4 __attribute__((ext_vector_type(4)));

static constexpr int NB = 2, SS = 2048, DD = 1024, NH = 16, HD = 64;

__device__ __forceinline__ void gl_lds16(const void* g, void* l) {
    __builtin_amdgcn_global_load_lds((__attribute__((address_space(1))) void*)g,
                                     (__attribute__((address_space(3))) void*)l, 16, 0, 0);
}

// ---------------- fused fp32 -> bf16 cast of h + Wq + Wk + Wv + Wo ----------------
__global__ __launch_bounds__(256) void cast_all(const float* __restrict__ h,
                                                const float* __restrict__ Wq,
                                                const float* __restrict__ Wk,
                                                const float* __restrict__ Wv,
                                                const float* __restrict__ Wo,
                                                bf16* __restrict__ dst) {
    int i = blockIdx.x * 256 + threadIdx.x;  // float4 index, grid covers exactly 2097152
    const float* src;
    int off;
    if (i < 1048576) { src = h; off = i; }
    else {
        int r = i - 1048576;
        int w = r >> 18;
        off = r & 262143;
        src = (w == 0) ? Wq : (w == 1) ? Wk : (w == 2) ? Wv : Wo;
    }
    float4 v = reinterpret_cast<const float4*>(src)[off];
    bf16x4_t o;
    o.x = (bf16)v.x; o.y = (bf16)v.y; o.z = (bf16)v.z; o.w = (bf16)v.w;
    reinterpret_cast<bf16x4_t*>(dst)[i] = o;
}

// ---------------- 128x128 NT-GEMM mainloop (m97 structure) ----------------
__device__ __forceinline__ void gemm128_mainloop(const bf16* __restrict__ Ablk,
                                                 const bf16* __restrict__ Bblk,
                                                 int K, f32x4 acc[4][4]) {
    __shared__ __align__(16) bf16 As[128 * 32];
    __shared__ __align__(16) bf16 Bs[128 * 32];
    const int tid = threadIdx.x;
    const int wave = tid >> 6, lane = tid & 63;
    const int quad = lane >> 4, l15 = lane & 15;
    const int wm = wave >> 1, wn = wave & 1;

#pragma unroll
    for (int mi = 0; mi < 4; mi++)
#pragma unroll
        for (int ni = 0; ni < 4; ni++) {
            acc[mi][ni][0] = 0.f; acc[mi][ni][1] = 0.f;
            acc[mi][ni][2] = 0.f; acc[mi][ni][3] = 0.f;
        }

    const int n0c = tid;
    const int r0 = n0c >> 2, c0 = (n0c & 3) ^ ((r0 >> 1) & 3);
    const int n1c = 256 + tid;
    const int r1 = n1c >> 2, c1 = (n1c & 3) ^ ((r1 >> 1) & 3);

    for (int kk = 0; kk < K; kk += 32) {
        __syncthreads();
        gl_lds16(Ablk + (size_t)r0 * K + kk + c0 * 8, &As[(wave * 64) * 8]);
        gl_lds16(Ablk + (size_t)r1 * K + kk + c1 * 8, &As[(256 + wave * 64) * 8]);
        gl_lds16(Bblk + (size_t)r0 * K + kk + c0 * 8, &Bs[(wave * 64) * 8]);
        gl_lds16(Bblk + (size_t)r1 * K + kk + c1 * 8, &Bs[(256 + wave * 64) * 8]);
        __syncthreads();

        bf16x8_t a[4], b[4];
#pragma unroll
        for (int mi = 0; mi < 4; mi++) {
            int R = wm * 64 + mi * 16 + l15;
            a[mi] = *(const bf16x8_t*)&As[R * 32 + ((quad ^ ((R >> 1) & 3)) << 3)];
        }
#pragma unroll
        for (int ni = 0; ni < 4; ni++) {
            int R = wn * 64 + ni * 16 + l15;
            b[ni] = *(const bf16x8_t*)&Bs[R * 32 + ((quad ^ ((R >> 1) & 3)) << 3)];
        }
#pragma unroll
        for (int mi = 0; mi < 4; mi++)
#pragma unroll
            for (int ni = 0; ni < 4; ni++)
                acc[mi][ni] = __builtin_amdgcn_mfma_f32_16x16x32_bf16(a[mi], b[ni], acc[mi][ni], 0, 0, 0);
    }
}

// ---------------- 64x128 NT-GEMM mainloop ----------------
__device__ __forceinline__ void gemm64_mainloop(const bf16* __restrict__ Ablk,
                                                const bf16* __restrict__ Bblk,
                                                int K, f32x4 acc[2][4]) {
    __shared__ __align__(16) bf16 As[64 * 32];
    __shared__ __align__(16) bf16 Bs[128 * 32];
    const int tid = threadIdx.x;
    const int wave = tid >> 6, lane = tid & 63;
    const int quad = lane >> 4, l15 = lane & 15;
    const int wm = wave >> 1, wn = wave & 1;

#pragma unroll
    for (int mi = 0; mi < 2; mi++)
#pragma unroll
        for (int ni = 0; ni < 4; ni++) {
            acc[mi][ni][0] = 0.f; acc[mi][ni][1] = 0.f;
            acc[mi][ni][2] = 0.f; acc[mi][ni][3] = 0.f;
        }

    const int ra = tid >> 2, ca = (tid & 3) ^ ((ra >> 1) & 3);
    const int r0 = tid >> 2, c0 = (tid & 3) ^ ((r0 >> 1) & 3);
    const int n1c = 256 + tid;
    const int r1 = n1c >> 2, c1 = (n1c & 3) ^ ((r1 >> 1) & 3);

    for (int kk = 0; kk < K; kk += 32) {
        __syncthreads();
        gl_lds16(Ablk + (size_t)ra * K + kk + ca * 8, &As[(wave * 64) * 8]);
        gl_lds16(Bblk + (size_t)r0 * K + kk + c0 * 8, &Bs[(wave * 64) * 8]);
        gl_lds16(Bblk + (size_t)r1 * K + kk + c1 * 8, &Bs[(256 + wave * 64) * 8]);
        __syncthreads();

        bf16x8_t a[2], b[4];
#pragma unroll
        for (int mi = 0; mi < 2; mi++) {
            int R = wm * 32 + mi * 16 + l15;
            a[mi] = *(const bf16x8_t*)&As[R * 32 + ((quad ^ ((R >> 1) & 3)) << 3)];
        }
#pragma unroll
        for (int ni = 0; ni < 4; ni++) {
            int R = wn * 64 + ni * 16 + l15;
            b[ni] = *(const bf16x8_t*)&Bs[R * 32 + ((quad ^ ((R >> 1) & 3)) << 3)];
        }
#pragma unroll
        for (int mi = 0; mi < 2; mi++)
#pragma unroll
            for (int ni = 0; ni < 4; ni++)
                acc[mi][ni] = __builtin_amdgcn_mfma_f32_16x16x32_bf16(a[mi], b[ni], acc[mi][ni], 0, 0, 0);
    }
}

// ---------------- QKV projection ----------------
// Q pre-scaled by 0.125*log2(e). V stored TRANSPOSED: Vb[bh][hd][s] so the
// attention kernel can DMA-stage V^T directly (no in-kernel transpose).
__global__ __launch_bounds__(256) void gemm_qkv(const bf16* __restrict__ A, const bf16* __restrict__ Wqkv,
                                                const float* __restrict__ bq, const float* __restrict__ bk,
                                                const float* __restrict__ bv,
                                                bf16* __restrict__ Qb, bf16* __restrict__ Kb, bf16* __restrict__ Vb) {
    const int m0 = blockIdx.x * 128;
    const int n0 = blockIdx.y * 128;
    f32x4 acc[4][4];
    gemm128_mainloop(A + (size_t)m0 * DD, Wqkv + (size_t)n0 * DD, DD, acc);

    const int tid = threadIdx.x, wave = tid >> 6, lane = tid & 63;
    const int quad = lane >> 4, l15 = lane & 15;
    const int wm = wave >> 1, wn = wave & 1;

    const int which = n0 >> 10;
    const float* bias = (which == 0) ? bq : (which == 1) ? bk : bv;
    const float sc = (which == 0) ? 0.18033688f : 1.0f;  // 0.125 * log2(e)

    const int cbase = (n0 & 1023) + wn * 64;
    const int head = cbase >> 6;
    const int bb = m0 >> 11;
    const int s0 = (m0 & 2047) + wm * 64;

    if (which == 2) {
        // V: transposed store [bh][hd][S], bf16x4 (4 consecutive s) per (mi,ni)
        bf16* dbase = Vb + ((size_t)(bb * NH + head)) * HD * SS;
#pragma unroll
        for (int ni = 0; ni < 4; ni++) {
            float bsv = bias[cbase + ni * 16 + l15];
            int hd = ni * 16 + l15;
#pragma unroll
            for (int mi = 0; mi < 4; mi++) {
                bf16x4_t pb;
                pb.x = (bf16)(acc[mi][ni][0] + bsv);
                pb.y = (bf16)(acc[mi][ni][1] + bsv);
                pb.z = (bf16)(acc[mi][ni][2] + bsv);
                pb.w = (bf16)(acc[mi][ni][3] + bsv);
                int s = s0 + mi * 16 + quad * 4;
                *(bf16x4_t*)&dbase[(size_t)hd * SS + s] = pb;
            }
        }
    } else {
        bf16* dst = (which == 0) ? Qb : Kb;
        bf16* dbase = dst + ((size_t)(bb * NH + head)) * SS * HD;
#pragma unroll
        for (int ni = 0; ni < 4; ni++) {
            float bsv = bias[cbase + ni * 16 + l15];
            int hd = ni * 16 + l15;
#pragma unroll
            for (int mi = 0; mi < 4; mi++) {
#pragma unroll
                for (int r = 0; r < 4; r++) {
                    int s = s0 + mi * 16 + quad * 4 + r;
                    dbase[(size_t)s * HD + hd] = (bf16)((acc[mi][ni][r] + bsv) * sc);
                }
            }
        }
    }
}

// ---------------- output projection: fp32 out, 64x128 tiles ----------------
__global__ __launch_bounds__(256) void gemm_out(const bf16* __restrict__ A, const bf16* __restrict__ Wo,
                                                const float* __restrict__ bo, float* __restrict__ out) {
    const int m0 = blockIdx.x * 64, n0 = blockIdx.y * 128;
    f32x4 acc[2][4];
    gemm64_mainloop(A + (size_t)m0 * DD, Wo + (size_t)n0 * DD, DD, acc);

    const int tid = threadIdx.x, wave = tid >> 6, lane = tid & 63;
    const int quad = lane >> 4, l15 = lane & 15;
    const int wm = wave >> 1, wn = wave & 1;
    float* obase = out + (size_t)(m0 + wm * 32) * DD + n0 + wn * 64;
#pragma unroll
    for (int ni = 0; ni < 4; ni++) {
        float bias = bo[n0 + wn * 64 + ni * 16 + l15];
#pragma unroll
        for (int mi = 0; mi < 2; mi++)
#pragma unroll
            for (int r = 0; r < 4; r++)
                obase[(size_t)(mi * 16 + quad * 4 + r) * DD + ni * 16 + l15] = acc[mi][ni][r] + bias;
    }
}

// ---------------- causal flash attention: static LPT schedule, all-DMA staging ----------------
// bh = bx&31 -> head h always on XCD h%8 (K/V 2 MB/XCD, L2-resident).
// Parts sorted strictly longest-first -> hardware refill gives greedy LPT
// balance. V^T staged by DMA from pre-transposed Vb (no VALU transpose).
// Split parts write unnormalized partials; separate merge kernel (kernel
// boundary = free device visibility, no fences).
__global__ __launch_bounds__(256, 3) void attn_kernel(const bf16* __restrict__ Qb, const bf16* __restrict__ Kb,
                                                      const bf16* __restrict__ Vb, bf16* __restrict__ Ob,
                                                      bf16* __restrict__ Opart, float* __restrict__ Ml) {
    // descending lengths: 10x8, 2x7, 2x6, 2x5, 2x4, 2x3, 2x2, 2x1 (sum 136/bh)
    constexpr int PQ[24]  = {15,14,13,12,11,10, 9, 8, 15, 7, 14, 6, 13, 5, 12, 4, 11, 3, 10, 2,  9, 1,  8, 0};
    constexpr int PJ0[24] = { 0, 0, 0, 0, 0, 0, 0, 0,  8, 0,  8, 0,  8, 0,  8, 0,  8, 0,  8, 0,  8, 0,  8, 0};
    constexpr int PJ1[24] = { 8, 8, 8, 8, 8, 8, 8, 8, 16, 8, 15, 7, 14, 6, 13, 5, 12, 4, 11, 3, 10, 2,  9, 1};

    __shared__ __align__(16) bf16 Kt[128 * 64];    // K tile, XOR-swizzled, DMA
    __shared__ __align__(16) bf16 Vt[64 * 128];    // V^T tile, XOR-swizzled, DMA
    __shared__ __align__(16) bf16 Pt[4 * 32 * 64]; // per-wave P strips, XOR-swizzled

    const int tid = threadIdx.x, wave = tid >> 6, lane = tid & 63;
    const int quad = lane >> 4, l15 = lane & 15;
    const int bx = blockIdx.x;
    const int p = bx >> 5, bh = bx & 31;
    const int qtile = PQ[p], jbeg = PJ0[p], jend = PJ1[p];
    const bool diagpart = (jend == qtile + 1);
    const size_t hoff = (size_t)bh * SS * HD;   // Q/K layout [bh][s][hd]
    const bf16* Qg = Qb + hoff + (size_t)qtile * 128 * HD;
    const bf16* Vbase = Vb + (size_t)bh * HD * SS;  // V layout [bh][hd][s]
    bf16* Pw = &Pt[wave * 2048];

    // Q B-frags (already scaled by 0.125*log2e)
    bf16x8_t qf[2][2];
#pragma unroll
    for (int qt = 0; qt < 2; qt++)
#pragma unroll
        for (int ks = 0; ks < 2; ks++)
            qf[qt][ks] = *(const bf16x8_t*)(Qg + (wave * 32 + qt * 16 + l15) * HD + ks * 32 + quad * 8);

    f32x4 o[2][4];
#pragma unroll
    for (int qt = 0; qt < 2; qt++)
#pragma unroll
        for (int nO = 0; nO < 4; nO++) {
            o[qt][nO][0] = 0.f; o[qt][nO][1] = 0.f; o[qt][nO][2] = 0.f; o[qt][nO][3] = 0.f;
        }
    float mrow[2] = {-__builtin_inff(), -__builtin_inff()};
    float lrow[2] = {0.f, 0.f};

    for (int j = jbeg; j < jend; j++) {
        __syncthreads();
        // K tile DMA: row chunk c' holds global chunk c'^(row&7)  (8 chunks/row)
        const bf16* Kg = Kb + hoff + (size_t)j * 128 * HD;
#pragma unroll
        for (int t = 0; t < 4; t++) {
            int n = t * 256 + tid;
            int row = n >> 3, gc = (n & 7) ^ (row & 7);
            gl_lds16(Kg + row * HD + gc * 8, &Kt[(t * 256 + wave * 64) * 8]);
        }
        // V^T tile DMA: row=hd, 16 chunks of 128 keys; chunk c' holds gc = c'^(row&15)
        const bf16* Vg = Vbase + j * 128;
#pragma unroll
        for (int t = 0; t < 4; t++) {
            int n = t * 256 + tid;
            int row = n >> 4, gc = (n & 15) ^ (row & 15);
            gl_lds16(Vg + (size_t)row * SS + gc * 8, &Vt[(t * 256 + wave * 64) * 8]);
        }
        __syncthreads();

        const bool diag = diagpart && (j == jend - 1);
#pragma unroll 1
        for (int kh = 0; kh < 2; kh++) {
            if (diag && kh == 1 && wave < 2) break;  // rows 0..63 fully masked vs keys 64..127

            // S^T = K * Q^T : st[kt][qt], key = kh*64 + kt*16 + quad*4 + r, qrow = qt*16 + l15
            f32x4 st[4][2];
#pragma unroll
            for (int kt = 0; kt < 4; kt++)
#pragma unroll
                for (int qt = 0; qt < 2; qt++) {
                    st[kt][qt][0] = 0.f; st[kt][qt][1] = 0.f; st[kt][qt][2] = 0.f; st[kt][qt][3] = 0.f;
                }
#pragma unroll
            for (int ks = 0; ks < 2; ks++) {
#pragma unroll
                for (int kt = 0; kt < 4; kt++) {
                    int R = (kh * 4 + kt) * 16 + l15;
                    bf16x8_t kf = *(const bf16x8_t*)&Kt[R * HD + ((((ks << 2) | quad) ^ (R & 7)) << 3)];
#pragma unroll
                    for (int qt = 0; qt < 2; qt++)
                        st[kt][qt] = __builtin_amdgcn_mfma_f32_16x16x32_bf16(kf, qf[qt][ks], st[kt][qt], 0, 0, 0);
                }
            }
            if (diag) {
#pragma unroll
                for (int kt = 0; kt < 4; kt++)
#pragma unroll
                    for (int qt = 0; qt < 2; qt++)
#pragma unroll
                        for (int r = 0; r < 4; r++) {
                            int key = kh * 64 + kt * 16 + quad * 4 + r;
                            int row = wave * 32 + qt * 16 + l15;
                            if (key > row) st[kt][qt][r] = -__builtin_inff();
                        }
            }

            // online softmax (log2 domain)
#pragma unroll
            for (int qt = 0; qt < 2; qt++) {
                float mx = -__builtin_inff();
#pragma unroll
                for (int kt = 0; kt < 4; kt++)
#pragma unroll
                    for (int r = 0; r < 4; r++) mx = fmaxf(mx, st[kt][qt][r]);
                mx = fmaxf(mx, __shfl_xor(mx, 16));
                mx = fmaxf(mx, __shfl_xor(mx, 32));
                float mnew = fmaxf(mrow[qt], mx);
                float alpha = exp2f(mrow[qt] - mnew);
                mrow[qt] = mnew;
                float sum = 0.f;
                const int row = qt * 16 + l15;
#pragma unroll
                for (int kt = 0; kt < 4; kt++) {
                    float p0 = exp2f(st[kt][qt][0] - mnew);
                    float p1 = exp2f(st[kt][qt][1] - mnew);
                    float p2 = exp2f(st[kt][qt][2] - mnew);
                    float p3 = exp2f(st[kt][qt][3] - mnew);
                    sum += (p0 + p1) + (p2 + p3);
                    bf16x4_t pb;
                    pb.x = (bf16)p0; pb.y = (bf16)p1; pb.z = (bf16)p2; pb.w = (bf16)p3;
                    int c = kt * 2 + (quad >> 1);
                    *(bf16x4_t*)&Pw[row * 64 + ((c ^ (row & 7)) << 3) + ((quad & 1) << 2)] = pb;
                }
                sum += __shfl_xor(sum, 16);
                sum += __shfl_xor(sum, 32);
                lrow[qt] = lrow[qt] * alpha + sum;
#pragma unroll
                for (int r = 0; r < 4; r++) {
                    float a = __shfl(alpha, (lane & 48) | (quad * 4 + r));
#pragma unroll
                    for (int nO = 0; nO < 4; nO++) o[qt][nO][r] *= a;
                }
            }

            // O += P * V^T-frags (V^T from swizzled DMA tile)
#pragma unroll
            for (int ks = 0; ks < 2; ks++) {
                bf16x8_t pf[2];
#pragma unroll
                for (int qt = 0; qt < 2; qt++) {
                    int row = qt * 16 + l15;
                    int c = (ks << 2) | quad;
                    pf[qt] = *(const bf16x8_t*)&Pw[row * 64 + ((c ^ (row & 7)) << 3)];
                }
#pragma unroll
                for (int nO = 0; nO < 4; nO++) {
                    int c = kh * 8 + ks * 4 + quad;  // 16-B chunk within V^T row
                    bf16x8_t vf = *(const bf16x8_t*)&Vt[(nO * 16 + l15) * 128 + ((c ^ l15) << 3)];
#pragma unroll
                    for (int qt = 0; qt < 2; qt++)
                        o[qt][nO] = __builtin_amdgcn_mfma_f32_16x16x32_bf16(pf[qt], vf, o[qt][nO], 0, 0, 0);
                }
            }
        }
    }

    const int bb = bh >> 4, hh = bh & 15;
    if (qtile >= 8) {
        // split part: write unnormalized O (bf16) + m,l (f32)
        const int pidx = ((bh << 3) + (qtile - 8)) * 2 + (jbeg != 0 ? 1 : 0);
        bf16* Op = Opart + (size_t)pidx * (128 * 64);
        float* mlp = Ml + (size_t)pidx * 256;
#pragma unroll
        for (int qt = 0; qt < 2; qt++) {
            if (quad == 0) {
                mlp[wave * 32 + qt * 16 + l15] = mrow[qt];
                mlp[128 + wave * 32 + qt * 16 + l15] = lrow[qt];
            }
#pragma unroll
            for (int r = 0; r < 4; r++) {
                int row = wave * 32 + qt * 16 + quad * 4 + r;
#pragma unroll
                for (int nO = 0; nO < 4; nO++)
                    Op[row * 64 + nO * 16 + l15] = (bf16)o[qt][nO][r];
            }
        }
    } else {
        // whole tile: normalize and write Ob [B, S, H*64]
#pragma unroll
        for (int qt = 0; qt < 2; qt++) {
#pragma unroll
            for (int r = 0; r < 4; r++) {
                float linv = 1.f / __shfl(lrow[qt], (lane & 48) | (quad * 4 + r));
                int srow = qtile * 128 + wave * 32 + qt * 16 + quad * 4 + r;
#pragma unroll
                for (int nO = 0; nO < 4; nO++)
                    Ob[((size_t)(bb * SS + srow)) * DD + hh * HD + nO * 16 + l15] = (bf16)(o[qt][nO][r] * linv);
            }
        }
    }
}

// ---------------- merge two KV-half partials -> Ob (qtiles 8..15) ----------------
__global__ __launch_bounds__(256) void merge_kernel(const bf16* __restrict__ Opart,
                                                    const float* __restrict__ Ml,
                                                    bf16* __restrict__ Ob) {
    const int bh = blockIdx.x >> 3, q8 = blockIdx.x & 7;  // qtile = 8 + q8
    const int p0 = ((bh << 3) + q8) * 2, p1 = p0 + 1;
    const int t = threadIdx.x, row = t >> 1, c0 = (t & 1) * 32;
    float m0 = Ml[p0 * 256 + row], l0 = Ml[p0 * 256 + 128 + row];
    float m1 = Ml[p1 * 256 + row], l1 = Ml[p1 * 256 + 128 + row];
    float M = fmaxf(m0, m1);
    float w0 = exp2f(m0 - M), w1 = exp2f(m1 - M);
    float inv = 1.f / (l0 * w0 + l1 * w1);
    w0 *= inv; w1 *= inv;
    const bf16* O0 = Opart + (size_t)p0 * (128 * 64) + row * 64 + c0;
    const bf16* O1 = Opart + (size_t)p1 * (128 * 64) + row * 64 + c0;
    const int bb = bh >> 4, hh = bh & 15;
    const int srow = (8 + q8) * 128 + row;
    bf16* dst = Ob + ((size_t)(bb * SS + srow)) * DD + hh * HD + c0;
#pragma unroll
    for (int i = 0; i < 4; i++) {
        bf16x8_t a = *(const bf16x8_t*)(O0 + i * 8);
        bf16x8_t b = *(const bf16x8_t*)(O1 + i * 8);
        bf16x8_t r;
#pragma unroll
        for (int jj = 0; jj < 8; jj++)
            r[jj] = (bf16)((float)a[jj] * w0 + (float)b[jj] * w1);
        *(bf16x8_t*)(dst + i * 8) = r;
    }
}

// ---------------- host launcher ----------------
extern "C" void kernel_launch(void* const* d_in, const int* in_sizes, int n_in,
                              void* d_out, int out_size, void* d_ws, size_t ws_size,
                              hipStream_t stream) {
    (void)in_sizes; (void)n_in; (void)out_size; (void)ws_size;
    const float* h  = (const float*)d_in[0];
    const float* Wq = (const float*)d_in[1];
    const float* bq = (const float*)d_in[2];
    const float* Wk = (const float*)d_in[3];
    const float* bk = (const float*)d_in[4];
    const float* Wv = (const float*)d_in[5];
    const float* bv = (const float*)d_in[6];
    const float* Wo = (const float*)d_in[7];
    const float* bo = (const float*)d_in[8];
    float* out = (float*)d_out;

    char* ws = (char*)d_ws;
    bf16* hbf  = (bf16*)(ws);                                  // 8,388,608  h bf16 (dead after gemm_qkv)
    bf16* wqkv = (bf16*)(ws + 8388608);                        // 6,291,456  Wq|Wk|Wv (dead after gemm_qkv)
    bf16* wo   = (bf16*)(ws + 8388608 + 6291456);              // 2,097,152  Wo
    bf16* Qb   = (bf16*)(ws + 16777216);                       // 8,388,608  [B,H,S,64] (scaled)
    bf16* Kb   = (bf16*)(ws + 16777216 + 8388608);             // [B,H,S,64]
    bf16* Vb   = (bf16*)(ws + 16777216 + 2 * 8388608);         // [B,H,64,S]  (transposed!)
    bf16* Ob   = (bf16*)(ws + 16777216 + 3 * 8388608);         // [B,S,H*64]
    // attention scratch reuses the dead cast region:
    bf16*  Opart = (bf16*)(ws);                                // 512 x 128x64 bf16 = 8,388,608
    float* Ml    = (float*)(ws + 8388608);                     // 512 x 256 f32   =   524,288

    cast_all<<<8192, 256, 0, stream>>>(h, Wq, Wk, Wv, Wo, hbf);
    gemm_qkv<<<dim3(32, 24), 256, 0, stream>>>(hbf, wqkv, bq, bk, bv, Qb, Kb, Vb);
    attn_kernel<<<768, 256, 0, stream>>>(Qb, Kb, Vb, Ob, Opart, Ml);
    merge_kernel<<<256, 256, 0, stream>>>(Opart, Ml, Ob);
    gemm_out<<<dim3(64, 8), 256, 0, stream>>>(Ob, wo, bo, out);
}